// Round 1
// baseline (261.753 us; speedup 1.0000x reference)
//
#include <hip/hip_runtime.h>
#include <math.h>

#define EPS 1e-5f

constexpr int Cc = 512;   // channels
constexpr int Dd = 64;    // proj dim

// One block per sample n. 256 threads.
__global__ __launch_bounds__(256) void fused_all(
    const float* __restrict__ x,
    const float* __restrict__ W123,
    const float* __restrict__ b123,
    const float* __restrict__ g123,
    const float* __restrict__ be123,
    const float* __restrict__ m123,
    const float* __restrict__ v123,
    const float* __restrict__ W4,
    const float* __restrict__ b4,
    const float* __restrict__ g4,
    const float* __restrict__ be4,
    const float* __restrict__ m4,
    const float* __restrict__ v4,
    float* __restrict__ out)
{
    constexpr int XST = 516;               // padded stride (floats) for xsT; 516*4B is 16B-aligned
    __shared__ float xsT[4 * XST];         // [p][c] subsampled input, transposed
    __shared__ float act[192 * 4];         // [(k*64+d)][p] post BN+ReLU
    __shared__ float sbuf[16];             // raw scores [l][m]
    __shared__ float attn_s[16];           // softmax'd [l][m]
    __shared__ float attT[4 * 68];         // [l][d] (padded stride 68; 272B is 16B-aligned)
    __shared__ float bn2[Cc * 4];          // [c][l]

    const int tid = threadIdx.x;
    const int n = blockIdx.x;
    const float* xn = x + (size_t)n * (Cc * 16);

    // ---- Phase 1: gather xs = x[n, :, ::2, ::2] into LDS as [p][c]
    // position p = hs*2 + ws over (h,w) in {(0,0),(0,2),(2,0),(2,2)} -> byte offsets {0,2,8,10} floats
    {
        for (int i = tid; i < 4 * Cc; i += 256) {
            int p = i >> 9;        // 0..3
            int c = i & 511;       // 0..511
            int off = ((p >> 1) * 8) + ((p & 1) * 2);   // 0,2,8,10
            xsT[p * XST + c] = xn[c * 16 + off];
        }
    }
    __syncthreads();

    // ---- Phase 2: proj[kd][p] = sum_c W123[kd][c] * xs[c][p]; BN + ReLU -> act
    // thread t handles rows kd0, kd0+64, kd0+128 at position p
    {
        const int kd0 = tid >> 2;          // 0..63
        const int p = tid & 3;
        const float4* wr0 = (const float4*)(W123 + (size_t)(kd0      ) * Cc);
        const float4* wr1 = (const float4*)(W123 + (size_t)(kd0 + 64 ) * Cc);
        const float4* wr2 = (const float4*)(W123 + (size_t)(kd0 + 128) * Cc);
        const float4* xv4 = (const float4*)(&xsT[p * XST]);
        float a0 = 0.f, a1 = 0.f, a2 = 0.f;
        #pragma unroll 4
        for (int q = 0; q < Cc / 4; ++q) {
            float4 xv = xv4[q];
            float4 w0 = wr0[q];
            float4 w1 = wr1[q];
            float4 w2 = wr2[q];
            a0 += w0.x * xv.x + w0.y * xv.y + w0.z * xv.z + w0.w * xv.w;
            a1 += w1.x * xv.x + w1.y * xv.y + w1.z * xv.z + w1.w * xv.w;
            a2 += w2.x * xv.x + w2.y * xv.y + w2.z * xv.z + w2.w * xv.w;
        }
        float accv[3] = {a0, a1, a2};
        #pragma unroll
        for (int j = 0; j < 3; ++j) {
            int kd = kd0 + j * 64;
            float sc = g123[kd] * rsqrtf(v123[kd] + EPS);
            float o = (accv[j] + b123[kd] - m123[kd]) * sc + be123[kd];
            act[kd * 4 + p] = fmaxf(o, 0.f);
        }
    }
    __syncthreads();

    // ---- Phase 3a: scores s[l][m] = sum_d q[l][d]*k[d][m] = sum_d act0[d][l]*act1[d][m]
    if (tid < 16) {
        int l = tid >> 2, m = tid & 3;
        float s = 0.f;
        for (int d = 0; d < Dd; ++d)
            s += act[d * 4 + l] * act[(64 + d) * 4 + m];
        sbuf[tid] = s;
    }
    __syncthreads();
    // softmax over m per row l
    if (tid < 4) {
        int l = tid;
        float s0 = sbuf[l*4+0], s1 = sbuf[l*4+1], s2 = sbuf[l*4+2], s3 = sbuf[l*4+3];
        float mx = fmaxf(fmaxf(s0, s1), fmaxf(s2, s3));
        float e0 = expf(s0 - mx), e1 = expf(s1 - mx), e2 = expf(s2 - mx), e3 = expf(s3 - mx);
        float inv = 1.f / (e0 + e1 + e2 + e3);
        attn_s[l*4+0] = e0 * inv;
        attn_s[l*4+1] = e1 * inv;
        attn_s[l*4+2] = e2 * inv;
        attn_s[l*4+3] = e3 * inv;
    }
    __syncthreads();

    // ---- Phase 3b: att[d][l] = sum_m attn[l][m] * act2[d][m]; store transposed attT[l][d]
    {
        int d = tid >> 2, l = tid & 3;
        float s = 0.f;
        #pragma unroll
        for (int m = 0; m < 4; ++m)
            s += attn_s[l*4 + m] * act[(128 + d)*4 + m];
        attT[l * 68 + d] = s;
    }
    __syncthreads();

    // ---- Phase 4: out2[c][l] = sum_d att[d][l]*W4[c][d] + b4[c]; BN2 -> bn2 LDS
    // thread t: l = t&3, c0 = t>>2; channels c0 + j*64, j=0..7
    {
        int l = tid & 3;
        int c0 = tid >> 2;                 // 0..63
        float acc[8] = {0,0,0,0,0,0,0,0};
        const float4* av4 = (const float4*)(&attT[l * 68]);
        #pragma unroll 4
        for (int q = 0; q < 16; ++q) {
            float4 av = av4[q];
            #pragma unroll
            for (int j = 0; j < 8; ++j) {
                int c = c0 + j * 64;
                float4 w = ((const float4*)(W4 + (size_t)c * 64))[q];
                acc[j] += w.x * av.x + w.y * av.y + w.z * av.z + w.w * av.w;
            }
        }
        #pragma unroll
        for (int j = 0; j < 8; ++j) {
            int c = c0 + j * 64;
            float o = acc[j] + b4[c];
            float sc = g4[c] * rsqrtf(v4[c] + EPS);
            bn2[c * 4 + l] = (o - m4[c]) * sc + be4[c];
        }
    }
    __syncthreads();

    // ---- Phase 5: out[n,c,h,w] = x[n,c,h,w] + bn2[c][h]  (broadcast over w)
    {
        const float4* x4 = (const float4*)xn;
        float4* o4 = (float4*)(out + (size_t)n * (Cc * 16));
        for (int j = tid; j < Cc * 4; j += 256) {
            float4 xv = x4[j];
            float b = bn2[(j >> 2) * 4 + (j & 3)];
            o4[j] = make_float4(xv.x + b, xv.y + b, xv.z + b, xv.w + b);
        }
    }
}

extern "C" void kernel_launch(void* const* d_in, const int* in_sizes, int n_in,
                              void* d_out, int out_size, void* d_ws, size_t ws_size,
                              hipStream_t stream) {
    const float* x     = (const float*)d_in[0];
    const float* W123  = (const float*)d_in[1];
    const float* b123  = (const float*)d_in[2];
    const float* g123  = (const float*)d_in[3];
    const float* be123 = (const float*)d_in[4];
    const float* m123  = (const float*)d_in[5];
    const float* v123  = (const float*)d_in[6];
    const float* W4    = (const float*)d_in[7];
    const float* b4    = (const float*)d_in[8];
    const float* g4    = (const float*)d_in[9];
    const float* be4   = (const float*)d_in[10];
    const float* m4    = (const float*)d_in[11];
    const float* v4    = (const float*)d_in[12];
    float* outp = (float*)d_out;

    fused_all<<<2048, 256, 0, stream>>>(x, W123, b123, g123, be123, m123, v123,
                                        W4, b4, g4, be4, m4, v4, outp);
}

// Round 4
// 216.435 us; speedup vs baseline: 1.2094x; 1.2094x over previous
//
#include <hip/hip_runtime.h>
#include <math.h>

#define EPS 1e-5f

// ---------------- K1: proj (C=512 -> 3x64) + BN + ReLU + 4x4 attention ----------------
// 4 samples per block, 256 threads, grid = 2048/4 = 512 blocks.
// Output: att_ws[n][l][d]  (n-major, 256 floats per sample, 2 MB total)
__global__ __launch_bounds__(256) void k1_proj_attn(
    const float* __restrict__ x,
    const float* __restrict__ W123,
    const float* __restrict__ b123,
    const float* __restrict__ g123,
    const float* __restrict__ be123,
    const float* __restrict__ m123,
    const float* __restrict__ v123,
    float* __restrict__ att_ws)
{
    __shared__ float xsT[16][516];     // [col = s*4 + p][c]; stride 516 (2064B, 16B-aligned, bank-skewed)
    __shared__ float act[4][192][4];   // [s][kd][p] post BN+ReLU
    __shared__ float smx[4][16];       // scores, then softmax probs, per sample

    const int tid = threadIdx.x;
    const int n0 = blockIdx.x * 4;

    // ---- P1: gather xs = x[n, :, ::2, ::2] for 4 samples, transposed into LDS
    // needed floats per channel: {0,2,8,10} -> two float4 loads, take .x/.z
    for (int i = tid; i < 2048; i += 256) {
        int s = i >> 9, c = i & 511;
        const float* xp = x + (size_t)(n0 + s) * 8192 + c * 16;
        float4 a = *(const float4*)xp;        // floats 0..3
        float4 b = *(const float4*)(xp + 8);  // floats 8..11
        xsT[s * 4 + 0][c] = a.x;
        xsT[s * 4 + 1][c] = a.z;
        xsT[s * 4 + 2][c] = b.x;
        xsT[s * 4 + 3][c] = b.z;
    }
    __syncthreads();

    // ---- P2: proj[kd][s][p] = sum_c W123[kd][c] * xs[s][c][p]; BN + ReLU -> act
    // thread t: kd0 = t>>2 (0..63) owns rows kd0, kd0+64, kd0+128; p = t&3; all 4 samples.
    {
        const int kd0 = tid >> 2, p = tid & 3;
        const float4* wr0 = (const float4*)(W123 + (size_t)kd0 * 512);
        const float4* wr1 = wr0 + 64 * 128;    // +64 rows
        const float4* wr2 = wr0 + 128 * 128;   // +128 rows
        float acc[3][4] = {};
        #pragma unroll 4
        for (int q = 0; q < 128; ++q) {
            float4 w0 = wr0[q], w1 = wr1[q], w2 = wr2[q];
            #pragma unroll
            for (int s = 0; s < 4; ++s) {
                float4 xv = *(const float4*)&xsT[s * 4 + p][q * 4];
                acc[0][s] += w0.x * xv.x + w0.y * xv.y + w0.z * xv.z + w0.w * xv.w;
                acc[1][s] += w1.x * xv.x + w1.y * xv.y + w1.z * xv.z + w1.w * xv.w;
                acc[2][s] += w2.x * xv.x + w2.y * xv.y + w2.z * xv.z + w2.w * xv.w;
            }
        }
        #pragma unroll
        for (int j = 0; j < 3; ++j) {
            int kd = kd0 + j * 64;
            float sc = g123[kd] * rsqrtf(v123[kd] + EPS);
            float sh = be123[kd] + (b123[kd] - m123[kd]) * sc;
            #pragma unroll
            for (int s = 0; s < 4; ++s)
                act[s][kd][p] = fmaxf(acc[j][s] * sc + sh, 0.f);
        }
    }
    __syncthreads();

    // ---- P3a: scores s[l][m] = sum_d q[d][l] * k[d][m]  (4 samples x 16 pairs = 64 threads)
    if (tid < 64) {
        int s = tid >> 4, l = (tid >> 2) & 3, m = tid & 3;
        float sum = 0.f;
        #pragma unroll 8
        for (int d = 0; d < 64; ++d)
            sum += act[s][d][l] * act[s][64 + d][m];
        smx[s][l * 4 + m] = sum;
    }
    __syncthreads();

    // ---- softmax over m (4 samples x 4 rows = 16 threads), in place
    if (tid < 16) {
        int s = tid >> 2, l = tid & 3;
        float s0 = smx[s][l * 4 + 0], s1 = smx[s][l * 4 + 1];
        float s2 = smx[s][l * 4 + 2], s3 = smx[s][l * 4 + 3];
        float mx = fmaxf(fmaxf(s0, s1), fmaxf(s2, s3));
        float e0 = expf(s0 - mx), e1 = expf(s1 - mx);
        float e2 = expf(s2 - mx), e3 = expf(s3 - mx);
        float inv = 1.f / (e0 + e1 + e2 + e3);
        smx[s][l * 4 + 0] = e0 * inv;
        smx[s][l * 4 + 1] = e1 * inv;
        smx[s][l * 4 + 2] = e2 * inv;
        smx[s][l * 4 + 3] = e3 * inv;
    }
    __syncthreads();

    // ---- P3b: att[l][d] = sum_m p[l][m] * v[d][m]; write att_ws[n][l*64+d] (coalesced)
    #pragma unroll
    for (int j = 0; j < 4; ++j) {
        int i = tid + 256 * j;             // i = s*256 + l*64 + d
        int s = i >> 8, l = (i >> 6) & 3, d = i & 63;
        float sum = 0.f;
        #pragma unroll
        for (int m = 0; m < 4; ++m)
            sum += smx[s][l * 4 + m] * act[s][128 + d][m];
        att_ws[(size_t)(n0 + s) * 256 + (i & 255)] = sum;
    }
}

// ---------------- K2: out2 = W4 @ att + BN2, residual add, stream x -> out ----------------
// 1 sample per block, 256 threads, no LDS, no barriers.
// thread t: l = t&3 (spatial row h), c0 = t>>2; owns channels c0 + 64j, j=0..7.
__global__ __launch_bounds__(256) void k2_out(
    const float* __restrict__ x,
    const float* __restrict__ att_ws,
    const float* __restrict__ W4,
    const float* __restrict__ b4,
    const float* __restrict__ g4,
    const float* __restrict__ be4,
    const float* __restrict__ m4,
    const float* __restrict__ v4,
    float* __restrict__ out)
{
    const int tid = threadIdx.x;
    const int n = blockIdx.x;
    const int l = tid & 3, c0 = tid >> 2;

    const float4* av4 = (const float4*)(att_ws + (size_t)n * 256 + l * 64);

    float accv[8] = {};
    #pragma unroll 2
    for (int q = 0; q < 16; ++q) {
        float4 av = av4[q];
        #pragma unroll
        for (int j = 0; j < 8; ++j) {
            float4 w = ((const float4*)(W4 + (size_t)(c0 + 64 * j) * 64))[q];
            accv[j] += w.x * av.x + w.y * av.y + w.z * av.z + w.w * av.w;
        }
    }

    const float* xn = x + (size_t)n * 8192;
    float* on = out + (size_t)n * 8192;
    #pragma unroll
    for (int j = 0; j < 8; ++j) {
        int c = c0 + 64 * j;
        float sc = g4[c] * rsqrtf(v4[c] + EPS);
        float b = (accv[j] + b4[c] - m4[c]) * sc + be4[c];
        float4 xv = *(const float4*)(xn + c * 16 + l * 4);
        float4 ov = make_float4(xv.x + b, xv.y + b, xv.z + b, xv.w + b);
        *(float4*)(on + c * 16 + l * 4) = ov;
    }
}

extern "C" void kernel_launch(void* const* d_in, const int* in_sizes, int n_in,
                              void* d_out, int out_size, void* d_ws, size_t ws_size,
                              hipStream_t stream) {
    const float* x     = (const float*)d_in[0];
    const float* W123  = (const float*)d_in[1];
    const float* b123  = (const float*)d_in[2];
    const float* g123  = (const float*)d_in[3];
    const float* be123 = (const float*)d_in[4];
    const float* m123  = (const float*)d_in[5];
    const float* v123  = (const float*)d_in[6];
    const float* W4    = (const float*)d_in[7];
    const float* b4    = (const float*)d_in[8];
    const float* g4    = (const float*)d_in[9];
    const float* be4   = (const float*)d_in[10];
    const float* m4    = (const float*)d_in[11];
    const float* v4    = (const float*)d_in[12];
    float* outp = (float*)d_out;
    float* att_ws = (float*)d_ws;   // 2048*256 floats = 2 MB

    k1_proj_attn<<<512, 256, 0, stream>>>(x, W123, b123, g123, be123, m123, v123, att_ws);
    k2_out<<<2048, 256, 0, stream>>>(x, att_ws, W4, b4, g4, be4, m4, v4, outp);
}

// Round 5
// 201.919 us; speedup vs baseline: 1.2963x; 1.0719x over previous
//
#include <hip/hip_runtime.h>
#include <math.h>

#define EPS 1e-5f

// Fully fused, 2 samples per block, 1024 blocks x 256 threads.
// LDS ~27KB -> 6 blocks/CU (24 waves/CU) for latency hiding.
__global__ __launch_bounds__(256) void fused2(
    const float* __restrict__ x,
    const float* __restrict__ W123,
    const float* __restrict__ b123,
    const float* __restrict__ g123,
    const float* __restrict__ be123,
    const float* __restrict__ m123,
    const float* __restrict__ v123,
    const float* __restrict__ W4,
    const float* __restrict__ b4,
    const float* __restrict__ g4,
    const float* __restrict__ be4,
    const float* __restrict__ m4,
    const float* __restrict__ v4,
    float* __restrict__ out)
{
    __shared__ float xsT[8][516];    // [s*4+p][c], padded stride (2064B, 16B-aligned)
    __shared__ float act[2][960];    // [s][kd*5+p]  (stride-5 pad -> <=2-way banks)
    __shared__ float smx[2][16];     // scores -> softmax probs
    __shared__ float attb[2][272];   // [s][l*68+d]  (272B rows, 16B-aligned)

    const int tid = threadIdx.x;
    const int n0 = blockIdx.x * 2;

    // ---- P1: gather xs = x[n, :, ::2, ::2], transposed into LDS
    #pragma unroll
    for (int it = 0; it < 4; ++it) {
        int i = tid + it * 256;            // i = s*512 + c
        int s = i >> 9, c = i & 511;
        const float* xp = x + (size_t)(n0 + s) * 8192 + c * 16;
        float4 a = *(const float4*)xp;         // floats 0..3 (h=0: w=0,2 -> .x,.z)
        float4 b = *(const float4*)(xp + 8);   // floats 8..11 (h=2)
        xsT[s * 4 + 0][c] = a.x;
        xsT[s * 4 + 1][c] = a.z;
        xsT[s * 4 + 2][c] = b.x;
        xsT[s * 4 + 3][c] = b.z;
    }
    __syncthreads();

    // ---- P2: proj[kd][s][p] = sum_c W123[kd][c]*xs[s][c][p]; BN+ReLU -> act
    {
        const int kd0 = tid >> 2, p = tid & 3;
        const float4* wr0 = (const float4*)(W123 + (size_t)kd0 * 512);
        const float4* wr1 = wr0 + 64 * 128;
        const float4* wr2 = wr0 + 128 * 128;
        float acc[3][2] = {};
        #pragma unroll 2
        for (int q = 0; q < 128; ++q) {
            float4 w0 = wr0[q], w1 = wr1[q], w2 = wr2[q];
            #pragma unroll
            for (int s = 0; s < 2; ++s) {
                float4 xv = *(const float4*)&xsT[s * 4 + p][q * 4];
                acc[0][s] += w0.x * xv.x + w0.y * xv.y + w0.z * xv.z + w0.w * xv.w;
                acc[1][s] += w1.x * xv.x + w1.y * xv.y + w1.z * xv.z + w1.w * xv.w;
                acc[2][s] += w2.x * xv.x + w2.y * xv.y + w2.z * xv.z + w2.w * xv.w;
            }
        }
        #pragma unroll
        for (int j = 0; j < 3; ++j) {
            int kd = kd0 + j * 64;
            float sc = g123[kd] * rsqrtf(v123[kd] + EPS);
            float sh = be123[kd] + (b123[kd] - m123[kd]) * sc;
            #pragma unroll
            for (int s = 0; s < 2; ++s)
                act[s][kd * 5 + p] = fmaxf(acc[j][s] * sc + sh, 0.f);
        }
    }
    __syncthreads();

    // ---- P3a: scores[l][m] = sum_d q[d][l]*k[d][m], wave-parallel (8 lanes per dot)
    {
        const int s = tid >> 7, l = (tid >> 5) & 3, m = (tid >> 3) & 3, dg = tid & 7;
        float part = 0.f;
        #pragma unroll
        for (int k = 0; k < 8; ++k) {
            int d = dg * 8 + k;
            part += act[s][d * 5 + l] * act[s][(64 + d) * 5 + m];
        }
        part += __shfl_xor(part, 1);
        part += __shfl_xor(part, 2);
        part += __shfl_xor(part, 4);
        if (dg == 0) smx[s][l * 4 + m] = part;
    }
    __syncthreads();

    // ---- softmax over m, in place (8 rows total)
    if (tid < 8) {
        int s = tid >> 2, l = tid & 3;
        float s0 = smx[s][l * 4 + 0], s1 = smx[s][l * 4 + 1];
        float s2 = smx[s][l * 4 + 2], s3 = smx[s][l * 4 + 3];
        float mx = fmaxf(fmaxf(s0, s1), fmaxf(s2, s3));
        float e0 = expf(s0 - mx), e1 = expf(s1 - mx);
        float e2 = expf(s2 - mx), e3 = expf(s3 - mx);
        float inv = 1.f / (e0 + e1 + e2 + e3);
        smx[s][l * 4 + 0] = e0 * inv;
        smx[s][l * 4 + 1] = e1 * inv;
        smx[s][l * 4 + 2] = e2 * inv;
        smx[s][l * 4 + 3] = e3 * inv;
    }
    __syncthreads();

    // ---- P3b: att[l][d] = sum_m p[l][m]*v[d][m] -> attb
    #pragma unroll
    for (int j = 0; j < 2; ++j) {
        int o = tid + 256 * j;             // o = s*256 + l*64 + d
        int s = o >> 8, l = (o >> 6) & 3, d = o & 63;
        float sum = 0.f;
        #pragma unroll
        for (int m = 0; m < 4; ++m)
            sum += smx[s][l * 4 + m] * act[s][(128 + d) * 5 + m];
        attb[s][l * 68 + d] = sum;
    }
    __syncthreads();

    // ---- P4: out2[c][l] = sum_d att[l][d]*W4[c][d]; BN2; P5: residual stream
    {
        const int c0 = tid >> 2, l = tid & 3;
        float acc[8][2] = {};
        for (int q = 0; q < 16; ++q) {
            float4 a0 = *(const float4*)&attb[0][l * 68 + q * 4];
            float4 a1 = *(const float4*)&attb[1][l * 68 + q * 4];
            #pragma unroll
            for (int j = 0; j < 8; ++j) {
                float4 w = ((const float4*)(W4 + (size_t)(c0 + 64 * j) * 64))[q];
                acc[j][0] += w.x * a0.x + w.y * a0.y + w.z * a0.z + w.w * a0.w;
                acc[j][1] += w.x * a1.x + w.y * a1.y + w.z * a1.z + w.w * a1.w;
            }
        }
        #pragma unroll
        for (int j = 0; j < 8; ++j) {
            int c = c0 + 64 * j;
            float sc = g4[c] * rsqrtf(v4[c] + EPS);
            float sh = (b4[c] - m4[c]) * sc + be4[c];
            #pragma unroll
            for (int s = 0; s < 2; ++s) {
                float b = acc[j][s] * sc + sh;
                const float* xp = x + (size_t)(n0 + s) * 8192 + c * 16 + l * 4;
                float* op = out + (size_t)(n0 + s) * 8192 + c * 16 + l * 4;
                float4 xv = *(const float4*)xp;
                *(float4*)op = make_float4(xv.x + b, xv.y + b, xv.z + b, xv.w + b);
            }
        }
    }
}

extern "C" void kernel_launch(void* const* d_in, const int* in_sizes, int n_in,
                              void* d_out, int out_size, void* d_ws, size_t ws_size,
                              hipStream_t stream) {
    const float* x     = (const float*)d_in[0];
    const float* W123  = (const float*)d_in[1];
    const float* b123  = (const float*)d_in[2];
    const float* g123  = (const float*)d_in[3];
    const float* be123 = (const float*)d_in[4];
    const float* m123  = (const float*)d_in[5];
    const float* v123  = (const float*)d_in[6];
    const float* W4    = (const float*)d_in[7];
    const float* b4    = (const float*)d_in[8];
    const float* g4    = (const float*)d_in[9];
    const float* be4   = (const float*)d_in[10];
    const float* m4    = (const float*)d_in[11];
    const float* v4    = (const float*)d_in[12];
    float* outp = (float*)d_out;

    fused2<<<1024, 256, 0, stream>>>(x, W123, b123, g123, be123, m123, v123,
                                     W4, b4, g4, be4, m4, v4, outp);
}

// Round 6
// 161.782 us; speedup vs baseline: 1.6179x; 1.2481x over previous
//
#include <hip/hip_runtime.h>
#include <hip/hip_bf16.h>
#include <math.h>

#define EPS 1e-5f

typedef __attribute__((ext_vector_type(8))) short bf8_t;   // 8 bf16 = MFMA A/B frag
typedef __attribute__((ext_vector_type(4))) float f4_t;    // MFMA C/D frag

static __device__ __forceinline__ unsigned short f2b(float f) {
    __hip_bfloat16 h = __float2bfloat16(f);
    return *reinterpret_cast<unsigned short*>(&h);
}

// ws layout (bytes):
//   0        : W1B  frag-linear bf16 of W123: idx ((mt*16+ks)*64+lane)*8+j  (196608 B)
//   196608   : W4B  frag-linear bf16 of W4:   idx ((mt*2+ks)*64+lane)*8+j   (65536 B)
//   262144   : bn1s[192], 262912: bn1h[192]
//   263680   : bn2s[512], 265728: bn2h[512]
//   524288   : bn2g[2048*512*4] fp32 (16.8 MB), layout [n][c][h]

// ---------------- K0: weight conversion to fragment-linear bf16 + BN folds ----------------
__global__ __launch_bounds__(256) void k0_prep(
    const float* __restrict__ W123, const float* __restrict__ W4,
    const float* __restrict__ b123, const float* __restrict__ g123,
    const float* __restrict__ be123, const float* __restrict__ m123, const float* __restrict__ v123,
    const float* __restrict__ b4, const float* __restrict__ g4,
    const float* __restrict__ be4, const float* __restrict__ m4, const float* __restrict__ v4,
    unsigned short* __restrict__ w1b, unsigned short* __restrict__ w4b,
    float* __restrict__ bn1s, float* __restrict__ bn1h,
    float* __restrict__ bn2s, float* __restrict__ bn2h)
{
    const int bid = blockIdx.x, tid = threadIdx.x;
    if (bid == 64) {
        if (tid < 192) {
            float s = g123[tid] * rsqrtf(v123[tid] + EPS);
            bn1s[tid] = s;
            bn1h[tid] = be123[tid] + (b123[tid] - m123[tid]) * s;
        }
        for (int c = tid; c < 512; c += 256) {
            float s = g4[c] * rsqrtf(v4[c] + EPS);
            bn2s[c] = s;
            bn2h[c] = be4[c] + (b4[c] - m4[c]) * s;
        }
        return;
    }
    const int f = bid * 256 + tid;     // 0..16383
    const float* src;
    unsigned short* dst;
    if (f < 12288) {                   // W123 frags: 12 mtiles x 16 ksteps x 64 lanes
        int mt = f >> 10, ks = (f >> 6) & 15, lane = f & 63;
        int row = mt * 16 + (lane & 15);
        int k0  = ks * 32 + ((lane >> 4) << 3);
        src = W123 + row * 512 + k0;
        dst = w1b + f * 8;
    } else {                           // W4 frags: 32 mtiles x 2 ksteps x 64 lanes
        int f2 = f - 12288;
        int mt = f2 >> 7, ks = (f2 >> 6) & 1, lane = f2 & 63;
        int row = mt * 16 + (lane & 15);
        int k0  = ks * 32 + ((lane >> 4) << 3);
        src = W4 + row * 64 + k0;
        dst = w4b + f2 * 8;
    }
    float4 a = *(const float4*)src;
    float4 b = *(const float4*)(src + 4);
    union { unsigned short u[8]; uint4 v; } o;
    o.u[0]=f2b(a.x); o.u[1]=f2b(a.y); o.u[2]=f2b(a.z); o.u[3]=f2b(a.w);
    o.u[4]=f2b(b.x); o.u[5]=f2b(b.y); o.u[6]=f2b(b.z); o.u[7]=f2b(b.w);
    *(uint4*)dst = o.v;
}

// ---------------- K1: MFMA proj + BN/ReLU + attention + MFMA W4 + BN2 -> bn2g ----------------
// 4 samples/block (16 cols = one 16-wide N-tile), 512 blocks x 256 threads (4 waves).
__global__ __launch_bounds__(256) void k1_mfma(
    const float* __restrict__ x,
    const unsigned short* __restrict__ w1b,
    const unsigned short* __restrict__ w4b,
    const float* __restrict__ bn1s, const float* __restrict__ bn1h,
    const float* __restrict__ bn2s, const float* __restrict__ bn2h,
    float* __restrict__ bn2g)
{
    __shared__ unsigned short Bxs[16][536];  // [col=s*4+p][k=c], pad->2-way banks on b128
    __shared__ float actL[192][17];          // [kd][col] post BN+ReLU
    __shared__ float smx[4][17];             // per-sample scores -> probs
    __shared__ unsigned short B2[16][72];    // att bf16 [col=s*4+l][k=d]
    __shared__ float C2T[16][524];           // bn2 transpose [col][c]

    const int tid = threadIdx.x;
    const int lane = tid & 63, w = tid >> 6;
    const int n0 = blockIdx.x * 4;

    // ---- P1: gather xs (4 samples), convert bf16, store k-major per col
    #pragma unroll
    for (int it = 0; it < 8; ++it) {
        int i = it * 256 + tid;            // i = s*512 + c
        int s = i >> 9, c = i & 511;
        const float* xp = x + (size_t)(n0 + s) * 8192 + c * 16;
        float4 a = *(const float4*)xp;         // h=0: w=0 -> .x, w=2 -> .z
        float4 b = *(const float4*)(xp + 8);   // h=2: w=0 -> .x, w=2 -> .z
        Bxs[s * 4 + 0][c] = f2b(a.x);
        Bxs[s * 4 + 1][c] = f2b(a.z);
        Bxs[s * 4 + 2][c] = f2b(b.x);
        Bxs[s * 4 + 3][c] = f2b(b.z);
    }
    __syncthreads();

    // ---- GEMM1: C1(192x16) = W123(192x512) @ XS(512x16), wave w owns mtiles w*3..w*3+2
    {
        f4_t acc[3] = {};
        const bf8_t* Af = (const bf8_t*)w1b;
        const int col = lane & 15, kg = (lane >> 4) << 3;
        for (int ks = 0; ks < 16; ++ks) {
            bf8_t bf = *(const bf8_t*)&Bxs[col][ks * 32 + kg];
            #pragma unroll
            for (int mi = 0; mi < 3; ++mi) {
                int mt = w * 3 + mi;
                bf8_t af = Af[(mt * 16 + ks) * 64 + lane];
                acc[mi] = __builtin_amdgcn_mfma_f32_16x16x32_bf16(af, bf, acc[mi], 0, 0, 0);
            }
        }
        // BN + ReLU, scatter to actL[row][col]
        #pragma unroll
        for (int mi = 0; mi < 3; ++mi) {
            int rbase = (w * 3 + mi) * 16 + ((lane >> 4) << 2);
            #pragma unroll
            for (int r = 0; r < 4; ++r) {
                int row = rbase + r;
                float v = acc[mi][r] * bn1s[row] + bn1h[row];
                actL[row][col] = fmaxf(v, 0.f);
            }
        }
    }
    __syncthreads();

    // ---- P3a: scores[l][m] = sum_d q[d][l]*k[d][m]  (threads 0..127; 2 lanes per dot)
    if (tid < 128) {
        int s = tid >> 5, l = (tid >> 3) & 3, m = (tid >> 1) & 3, dg = tid & 1;
        float part = 0.f;
        #pragma unroll 8
        for (int k = 0; k < 32; ++k) {
            int d = dg * 32 + k;
            part += actL[d][s * 4 + l] * actL[64 + d][s * 4 + m];
        }
        part += __shfl_xor(part, 1);
        if (dg == 0) smx[s][l * 4 + m] = part;
    }
    __syncthreads();

    // ---- softmax rows (threads 0..15)
    if (tid < 16) {
        int s = tid >> 2, l = tid & 3;
        float s0 = smx[s][l*4+0], s1 = smx[s][l*4+1], s2 = smx[s][l*4+2], s3 = smx[s][l*4+3];
        float mx = fmaxf(fmaxf(s0, s1), fmaxf(s2, s3));
        float e0 = expf(s0-mx), e1 = expf(s1-mx), e2 = expf(s2-mx), e3 = expf(s3-mx);
        float inv = 1.f / (e0 + e1 + e2 + e3);
        smx[s][l*4+0] = e0*inv; smx[s][l*4+1] = e1*inv;
        smx[s][l*4+2] = e2*inv; smx[s][l*4+3] = e3*inv;
    }
    __syncthreads();

    // ---- P3b: att[s][l][d] = sum_m p[l][m]*v[d][m] -> B2 bf16 [col=s*4+l][k=d]
    if (tid < 128) {
        int s = tid >> 5, l = (tid >> 3) & 3, d0 = (tid & 7) * 8;
        float p0 = smx[s][l*4+0], p1 = smx[s][l*4+1], p2 = smx[s][l*4+2], p3 = smx[s][l*4+3];
        #pragma unroll
        for (int j = 0; j < 8; ++j) {
            int d = d0 + j;
            float sum = p0 * actL[128+d][s*4+0] + p1 * actL[128+d][s*4+1]
                      + p2 * actL[128+d][s*4+2] + p3 * actL[128+d][s*4+3];
            B2[s * 4 + l][d] = f2b(sum);
        }
    }
    __syncthreads();

    // ---- GEMM2: C2(512x16) = W4(512x64) @ att(64x16); wave w owns mtiles w*8..w*8+7
    {
        const bf8_t* A2f = (const bf8_t*)w4b;
        const int col = lane & 15, kg = (lane >> 4) << 3;
        f4_t acc2[8] = {};
        #pragma unroll
        for (int ks = 0; ks < 2; ++ks) {
            bf8_t bf = *(const bf8_t*)&B2[col][ks * 32 + kg];
            #pragma unroll
            for (int mi = 0; mi < 8; ++mi) {
                int mt = w * 8 + mi;
                bf8_t af = A2f[(mt * 2 + ks) * 64 + lane];
                acc2[mi] = __builtin_amdgcn_mfma_f32_16x16x32_bf16(af, bf, acc2[mi], 0, 0, 0);
            }
        }
        // BN2, write transposed into C2T[col][c]
        #pragma unroll
        for (int mi = 0; mi < 8; ++mi) {
            int cbase = (w * 8 + mi) * 16 + ((lane >> 4) << 2);
            #pragma unroll
            for (int r = 0; r < 4; ++r) {
                int c = cbase + r;
                C2T[col][c] = acc2[mi][r] * bn2s[c] + bn2h[c];
            }
        }
    }
    __syncthreads();

    // ---- store bn2g[n][c][l] coalesced (float4 over l)
    #pragma unroll
    for (int it = 0; it < 8; ++it) {
        int j = it * 256 + tid;            // j = s*512 + c
        int s = j >> 9, c = j & 511;
        float4 v = make_float4(C2T[s*4+0][c], C2T[s*4+1][c], C2T[s*4+2][c], C2T[s*4+3][c]);
        *(float4*)(bn2g + (size_t)(n0 + s) * 2048 + c * 4) = v;
    }
}

// ---------------- K2: out = x + bn2 broadcast over w (pure stream) ----------------
__global__ __launch_bounds__(256) void k2_stream(
    const float* __restrict__ x,
    const float* __restrict__ bn2g,
    float* __restrict__ out)
{
    int i = blockIdx.x * 256 + threadIdx.x;
    #pragma unroll
    for (int it = 0; it < 8; ++it, i += 524288) {
        float4 xv = ((const float4*)x)[i];
        float b = bn2g[i];                 // float4 index == n*2048 + c*4 + h == bn2 flat idx
        ((float4*)out)[i] = make_float4(xv.x + b, xv.y + b, xv.z + b, xv.w + b);
    }
}

extern "C" void kernel_launch(void* const* d_in, const int* in_sizes, int n_in,
                              void* d_out, int out_size, void* d_ws, size_t ws_size,
                              hipStream_t stream) {
    const float* x     = (const float*)d_in[0];
    const float* W123  = (const float*)d_in[1];
    const float* b123  = (const float*)d_in[2];
    const float* g123  = (const float*)d_in[3];
    const float* be123 = (const float*)d_in[4];
    const float* m123  = (const float*)d_in[5];
    const float* v123  = (const float*)d_in[6];
    const float* W4    = (const float*)d_in[7];
    const float* b4    = (const float*)d_in[8];
    const float* g4    = (const float*)d_in[9];
    const float* be4   = (const float*)d_in[10];
    const float* m4    = (const float*)d_in[11];
    const float* v4    = (const float*)d_in[12];
    float* outp = (float*)d_out;

    char* ws = (char*)d_ws;
    unsigned short* w1b = (unsigned short*)ws;
    unsigned short* w4b = (unsigned short*)(ws + 196608);
    float* bn1s = (float*)(ws + 262144);
    float* bn1h = (float*)(ws + 262912);
    float* bn2s = (float*)(ws + 263680);
    float* bn2h = (float*)(ws + 265728);
    float* bn2g = (float*)(ws + 524288);   // 16.8 MB

    k0_prep<<<65, 256, 0, stream>>>(W123, W4, b123, g123, be123, m123, v123,
                                    b4, g4, be4, m4, v4,
                                    w1b, w4b, bn1s, bn1h, bn2s, bn2h);
    k1_mfma<<<512, 256, 0, stream>>>(x, w1b, w4b, bn1s, bn1h, bn2s, bn2h, bn2g);
    k2_stream<<<2048, 256, 0, stream>>>(x, bn2g, outp);
}

// Round 7
// 152.646 us; speedup vs baseline: 1.7148x; 1.0599x over previous
//
#include <hip/hip_runtime.h>
#include <hip/hip_bf16.h>
#include <math.h>

#define EPS 1e-5f

typedef __attribute__((ext_vector_type(8))) short bf8_t;   // 8 bf16 = MFMA A/B frag
typedef __attribute__((ext_vector_type(4))) float f4_t;    // MFMA C/D frag

static __device__ __forceinline__ unsigned short f2b(float f) {
    __hip_bfloat16 h = __float2bfloat16(f);
    return *reinterpret_cast<unsigned short*>(&h);
}

// ws layout (bytes):
//   0        : W1B  frag-linear bf16 of W123: idx ((mt*16+ks)*64+lane)*8+j  (196608 B)
//   196608   : W4B  frag-linear bf16 of W4:   idx ((mt*2+ks)*64+lane)*8+j   (65536 B)
//   262144   : bn1s[192], 262912: bn1h[192]
//   263680   : bn2s[512], 265728: bn2h[512]

// ---------------- K0: weight conversion to fragment-linear bf16 + BN folds ----------------
__global__ __launch_bounds__(256) void k0_prep(
    const float* __restrict__ W123, const float* __restrict__ W4,
    const float* __restrict__ b123, const float* __restrict__ g123,
    const float* __restrict__ be123, const float* __restrict__ m123, const float* __restrict__ v123,
    const float* __restrict__ b4, const float* __restrict__ g4,
    const float* __restrict__ be4, const float* __restrict__ m4, const float* __restrict__ v4,
    unsigned short* __restrict__ w1b, unsigned short* __restrict__ w4b,
    float* __restrict__ bn1s, float* __restrict__ bn1h,
    float* __restrict__ bn2s, float* __restrict__ bn2h)
{
    const int bid = blockIdx.x, tid = threadIdx.x;
    if (bid == 64) {
        if (tid < 192) {
            float s = g123[tid] * rsqrtf(v123[tid] + EPS);
            bn1s[tid] = s;
            bn1h[tid] = be123[tid] + (b123[tid] - m123[tid]) * s;
        }
        for (int c = tid; c < 512; c += 256) {
            float s = g4[c] * rsqrtf(v4[c] + EPS);
            bn2s[c] = s;
            bn2h[c] = be4[c] + (b4[c] - m4[c]) * s;
        }
        return;
    }
    const int f = bid * 256 + tid;     // 0..16383
    const float* src;
    unsigned short* dst;
    if (f < 12288) {                   // W123 frags: 12 mtiles x 16 ksteps x 64 lanes
        int mt = f >> 10, ks = (f >> 6) & 15, lane = f & 63;
        int row = mt * 16 + (lane & 15);
        int k0  = ks * 32 + ((lane >> 4) << 3);
        src = W123 + row * 512 + k0;
        dst = w1b + f * 8;
    } else {                           // W4 frags: 32 mtiles x 2 ksteps x 64 lanes
        int f2 = f - 12288;
        int mt = f2 >> 7, ks = (f2 >> 6) & 1, lane = f2 & 63;
        int row = mt * 16 + (lane & 15);
        int k0  = ks * 32 + ((lane >> 4) << 3);
        src = W4 + row * 64 + k0;
        dst = w4b + f2 * 8;
    }
    float4 a = *(const float4*)src;
    float4 b = *(const float4*)(src + 4);
    union { unsigned short u[8]; uint4 v; } o;
    o.u[0]=f2b(a.x); o.u[1]=f2b(a.y); o.u[2]=f2b(a.z); o.u[3]=f2b(a.w);
    o.u[4]=f2b(b.x); o.u[5]=f2b(b.y); o.u[6]=f2b(b.z); o.u[7]=f2b(b.w);
    *(uint4*)dst = o.v;
}

// ---------------- K1: MFMA proj + BN/ReLU + attention + MFMA W4 + BN2 + residual ----------------
// 4 samples/block (16 cols = one 16-wide N-tile), 512 blocks x 256 threads (4 waves).
// LDS ~33KB -> 4 blocks/CU (16 waves/CU).
__global__ __launch_bounds__(256) void k1_mfma(
    const float* __restrict__ x,
    const unsigned short* __restrict__ w1b,
    const unsigned short* __restrict__ w4b,
    const float* __restrict__ bn1s, const float* __restrict__ bn1h,
    const float* __restrict__ bn2s, const float* __restrict__ bn2h,
    float* __restrict__ out)
{
    __shared__ unsigned short Bxs[16][536];  // [col=s*4+p][k=c], pad->2-way banks on b128
    __shared__ float actL[192][17];          // [kd][col] post BN+ReLU
    __shared__ float smx[4][17];             // per-sample scores -> probs
    __shared__ unsigned short B2[16][72];    // att bf16 [col=s*4+l][k=d]

    const int tid = threadIdx.x;
    const int lane = tid & 63, w = tid >> 6;
    const int n0 = blockIdx.x * 4;

    // ---- P1: gather xs (4 samples), convert bf16, store k-major per col
    #pragma unroll
    for (int it = 0; it < 8; ++it) {
        int i = it * 256 + tid;            // i = s*512 + c
        int s = i >> 9, c = i & 511;
        const float* xp = x + (size_t)(n0 + s) * 8192 + c * 16;
        float4 a = *(const float4*)xp;         // h=0: w=0 -> .x, w=2 -> .z
        float4 b = *(const float4*)(xp + 8);   // h=2: w=0 -> .x, w=2 -> .z
        Bxs[s * 4 + 0][c] = f2b(a.x);
        Bxs[s * 4 + 1][c] = f2b(a.z);
        Bxs[s * 4 + 2][c] = f2b(b.x);
        Bxs[s * 4 + 3][c] = f2b(b.z);
    }
    __syncthreads();

    // ---- GEMM1: C1(192x16) = W123(192x512) @ XS(512x16), wave w owns mtiles w*3..w*3+2
    {
        f4_t acc[3] = {};
        const bf8_t* Af = (const bf8_t*)w1b;
        const int col = lane & 15, kg = (lane >> 4) << 3;
        for (int ks = 0; ks < 16; ++ks) {
            bf8_t bf = *(const bf8_t*)&Bxs[col][ks * 32 + kg];
            #pragma unroll
            for (int mi = 0; mi < 3; ++mi) {
                int mt = w * 3 + mi;
                bf8_t af = Af[(mt * 16 + ks) * 64 + lane];
                acc[mi] = __builtin_amdgcn_mfma_f32_16x16x32_bf16(af, bf, acc[mi], 0, 0, 0);
            }
        }
        // BN + ReLU, scatter to actL[row][col]
        #pragma unroll
        for (int mi = 0; mi < 3; ++mi) {
            int rbase = (w * 3 + mi) * 16 + ((lane >> 4) << 2);
            #pragma unroll
            for (int r = 0; r < 4; ++r) {
                int row = rbase + r;
                float v = acc[mi][r] * bn1s[row] + bn1h[row];
                actL[row][col] = fmaxf(v, 0.f);
            }
        }
    }
    __syncthreads();

    // ---- P3a: scores[l][m] = sum_d q[d][l]*k[d][m]  (threads 0..127; 2 lanes per dot)
    if (tid < 128) {
        int s = tid >> 5, l = (tid >> 3) & 3, m = (tid >> 1) & 3, dg = tid & 1;
        float part = 0.f;
        #pragma unroll 8
        for (int k = 0; k < 32; ++k) {
            int d = dg * 32 + k;
            part += actL[d][s * 4 + l] * actL[64 + d][s * 4 + m];
        }
        part += __shfl_xor(part, 1);
        if (dg == 0) smx[s][l * 4 + m] = part;
    }
    __syncthreads();

    // ---- softmax rows (threads 0..15)
    if (tid < 16) {
        int s = tid >> 2, l = tid & 3;
        float s0 = smx[s][l*4+0], s1 = smx[s][l*4+1], s2 = smx[s][l*4+2], s3 = smx[s][l*4+3];
        float mx = fmaxf(fmaxf(s0, s1), fmaxf(s2, s3));
        float e0 = expf(s0-mx), e1 = expf(s1-mx), e2 = expf(s2-mx), e3 = expf(s3-mx);
        float inv = 1.f / (e0 + e1 + e2 + e3);
        smx[s][l*4+0] = e0*inv; smx[s][l*4+1] = e1*inv;
        smx[s][l*4+2] = e2*inv; smx[s][l*4+3] = e3*inv;
    }
    __syncthreads();

    // ---- P3b: att[s][l][d] = sum_m p[l][m]*v[d][m] -> B2 bf16 [col=s*4+l][k=d]
    if (tid < 128) {
        int s = tid >> 5, l = (tid >> 3) & 3, d0 = (tid & 7) * 8;
        float p0 = smx[s][l*4+0], p1 = smx[s][l*4+1], p2 = smx[s][l*4+2], p3 = smx[s][l*4+3];
        #pragma unroll
        for (int j = 0; j < 8; ++j) {
            int d = d0 + j;
            float sum = p0 * actL[128+d][s*4+0] + p1 * actL[128+d][s*4+1]
                      + p2 * actL[128+d][s*4+2] + p3 * actL[128+d][s*4+3];
            B2[s * 4 + l][d] = f2b(sum);
        }
    }
    __syncthreads();

    // ---- GEMM2: C2(512x16) = W4(512x64) @ att(64x16); wave w owns mtiles w*8..w*8+7
    // then BN2 + residual DIRECT from registers:
    //   lane layout: col = lane&15 -> (s = col>>2, l = col&3); rows c = mt*16 + (lane>>4)*4 + r
    //   out addr = (n0+s)*8192 + c*16 + l*4 : lanes 0..3 cover one 64B segment -> coalesced
    {
        const bf8_t* A2f = (const bf8_t*)w4b;
        const int col = lane & 15, kg = (lane >> 4) << 3;
        f4_t acc2[8] = {};
        #pragma unroll
        for (int ks = 0; ks < 2; ++ks) {
            bf8_t bf = *(const bf8_t*)&B2[col][ks * 32 + kg];
            #pragma unroll
            for (int mi = 0; mi < 8; ++mi) {
                int mt = w * 8 + mi;
                bf8_t af = A2f[(mt * 2 + ks) * 64 + lane];
                acc2[mi] = __builtin_amdgcn_mfma_f32_16x16x32_bf16(af, bf, acc2[mi], 0, 0, 0);
            }
        }
        const int s = col >> 2, l = col & 3;
        const float* xn = x + (size_t)(n0 + s) * 8192 + l * 4;
        float* on = out + (size_t)(n0 + s) * 8192 + l * 4;
        #pragma unroll
        for (int mi = 0; mi < 8; ++mi) {
            int cbase = (w * 8 + mi) * 16 + ((lane >> 4) << 2);
            #pragma unroll
            for (int r = 0; r < 4; ++r) {
                int c = cbase + r;
                float b = acc2[mi][r] * bn2s[c] + bn2h[c];
                float4 xv = *(const float4*)(xn + c * 16);
                *(float4*)(on + c * 16) = make_float4(xv.x + b, xv.y + b, xv.z + b, xv.w + b);
            }
        }
    }
}

extern "C" void kernel_launch(void* const* d_in, const int* in_sizes, int n_in,
                              void* d_out, int out_size, void* d_ws, size_t ws_size,
                              hipStream_t stream) {
    const float* x     = (const float*)d_in[0];
    const float* W123  = (const float*)d_in[1];
    const float* b123  = (const float*)d_in[2];
    const float* g123  = (const float*)d_in[3];
    const float* be123 = (const float*)d_in[4];
    const float* m123  = (const float*)d_in[5];
    const float* v123  = (const float*)d_in[6];
    const float* W4    = (const float*)d_in[7];
    const float* b4    = (const float*)d_in[8];
    const float* g4    = (const float*)d_in[9];
    const float* be4   = (const float*)d_in[10];
    const float* m4    = (const float*)d_in[11];
    const float* v4    = (const float*)d_in[12];
    float* outp = (float*)d_out;

    char* ws = (char*)d_ws;
    unsigned short* w1b = (unsigned short*)ws;
    unsigned short* w4b = (unsigned short*)(ws + 196608);
    float* bn1s = (float*)(ws + 262144);
    float* bn1h = (float*)(ws + 262912);
    float* bn2s = (float*)(ws + 263680);
    float* bn2h = (float*)(ws + 265728);

    k0_prep<<<65, 256, 0, stream>>>(W123, W4, b123, g123, be123, m123, v123,
                                    b4, g4, be4, m4, v4,
                                    w1b, w4b, bn1s, bn1h, bn2s, bn2h);
    k1_mfma<<<512, 256, 0, stream>>>(x, w1b, w4b, bn1s, bn1h, bn2s, bn2h, outp);
}

// Round 8
// 152.086 us; speedup vs baseline: 1.7211x; 1.0037x over previous
//
#include <hip/hip_runtime.h>
#include <hip/hip_bf16.h>
#include <math.h>

#define EPS 1e-5f

typedef __attribute__((ext_vector_type(8))) short bf8_t;   // 8 bf16 = MFMA A/B frag
typedef __attribute__((ext_vector_type(4))) float f4_t;    // MFMA C/D frag

static __device__ __forceinline__ unsigned short f2b(float f) {
    __hip_bfloat16 h = __float2bfloat16(f);
    return *reinterpret_cast<unsigned short*>(&h);
}

// ws layout (bytes):
//   0        : W1B  frag-linear bf16 of W123: idx ((mt*16+ks)*64+lane)*8+j  (196608 B)
//   196608   : W4B  frag-linear bf16 of W4:   idx ((mt*2+ks)*64+lane)*8+j   (65536 B)
//   262144   : bn1s[192], 262912: bn1h[192]
//   263680   : bn2s[512], 265728: bn2h[512]

// ---------------- K0: weight conversion to fragment-linear bf16 + BN folds ----------------
__global__ __launch_bounds__(256) void k0_prep(
    const float* __restrict__ W123, const float* __restrict__ W4,
    const float* __restrict__ b123, const float* __restrict__ g123,
    const float* __restrict__ be123, const float* __restrict__ m123, const float* __restrict__ v123,
    const float* __restrict__ b4, const float* __restrict__ g4,
    const float* __restrict__ be4, const float* __restrict__ m4, const float* __restrict__ v4,
    unsigned short* __restrict__ w1b, unsigned short* __restrict__ w4b,
    float* __restrict__ bn1s, float* __restrict__ bn1h,
    float* __restrict__ bn2s, float* __restrict__ bn2h)
{
    const int bid = blockIdx.x, tid = threadIdx.x;
    if (bid == 64) {
        if (tid < 192) {
            float s = g123[tid] * rsqrtf(v123[tid] + EPS);
            bn1s[tid] = s;
            bn1h[tid] = be123[tid] + (b123[tid] - m123[tid]) * s;
        }
        for (int c = tid; c < 512; c += 256) {
            float s = g4[c] * rsqrtf(v4[c] + EPS);
            bn2s[c] = s;
            bn2h[c] = be4[c] + (b4[c] - m4[c]) * s;
        }
        return;
    }
    const int f = bid * 256 + tid;     // 0..16383
    const float* src;
    unsigned short* dst;
    if (f < 12288) {                   // W123 frags: 12 mtiles x 16 ksteps x 64 lanes
        int mt = f >> 10, ks = (f >> 6) & 15, lane = f & 63;
        int row = mt * 16 + (lane & 15);
        int k0  = ks * 32 + ((lane >> 4) << 3);
        src = W123 + row * 512 + k0;
        dst = w1b + f * 8;
    } else {                           // W4 frags: 32 mtiles x 2 ksteps x 64 lanes
        int f2 = f - 12288;
        int mt = f2 >> 7, ks = (f2 >> 6) & 1, lane = f2 & 63;
        int row = mt * 16 + (lane & 15);
        int k0  = ks * 32 + ((lane >> 4) << 3);
        src = W4 + row * 64 + k0;
        dst = w4b + f2 * 8;
    }
    float4 a = *(const float4*)src;
    float4 b = *(const float4*)(src + 4);
    union { unsigned short u[8]; uint4 v; } o;
    o.u[0]=f2b(a.x); o.u[1]=f2b(a.y); o.u[2]=f2b(a.z); o.u[3]=f2b(a.w);
    o.u[4]=f2b(b.x); o.u[5]=f2b(b.y); o.u[6]=f2b(b.z); o.u[7]=f2b(b.w);
    *(uint4*)dst = o.v;
}

// ---------------- K1: MFMA proj + BN/ReLU + attention + MFMA W4 + BN2 + residual ----------------
// 2 samples/block (cols 0-7 of the 16-wide N-tile), 1024 blocks x 256 threads (4 waves).
// LDS ~34KB -> 4 blocks/CU (16 waves/CU).
__global__ __launch_bounds__(256) void k1_mfma(
    const float* __restrict__ x,
    const unsigned short* __restrict__ w1b,
    const unsigned short* __restrict__ w4b,
    const float* __restrict__ bn1s, const float* __restrict__ bn1h,
    const float* __restrict__ bn2s, const float* __restrict__ bn2h,
    float* __restrict__ out)
{
    __shared__ unsigned short Bxs[8][536];   // [col=s*4+p][k=c]
    __shared__ float actL[192][9];           // [kd][col] post BN+ReLU (stride 9: odd -> conflict-free)
    __shared__ float smx[2][17];             // per-sample scores -> probs
    __shared__ unsigned short B2[8][72];     // att bf16 [col=s*4+l][k=d]
    __shared__ float C2T[8][524];            // bn2 [col=s*4+h][c]

    const int tid = threadIdx.x;
    const int lane = tid & 63, w = tid >> 6;
    const int n0 = blockIdx.x * 2;

    // ---- P1: gather xs (2 samples), convert bf16, store k-major per col
    #pragma unroll
    for (int it = 0; it < 4; ++it) {
        int i = it * 256 + tid;            // i = s*512 + c
        int s = i >> 9, c = i & 511;
        const float* xp = x + (size_t)(n0 + s) * 8192 + c * 16;
        float4 a = *(const float4*)xp;         // h=0: w=0 -> .x, w=2 -> .z
        float4 b = *(const float4*)(xp + 8);   // h=2: w=0 -> .x, w=2 -> .z
        Bxs[s * 4 + 0][c] = f2b(a.x);
        Bxs[s * 4 + 1][c] = f2b(a.z);
        Bxs[s * 4 + 2][c] = f2b(b.x);
        Bxs[s * 4 + 3][c] = f2b(b.z);
    }
    __syncthreads();

    // ---- GEMM1: C1(192x8) = W123(192x512) @ XS(512x8), wave w owns mtiles w*3..w*3+2
    {
        f4_t acc[3] = {};
        const bf8_t* Af = (const bf8_t*)w1b;
        const int col = lane & 15, kg = (lane >> 4) << 3;
        for (int ks = 0; ks < 16; ++ks) {
            bf8_t bf = *(const bf8_t*)&Bxs[col & 7][ks * 32 + kg];  // cols 8-15 duplicate 0-7
            #pragma unroll
            for (int mi = 0; mi < 3; ++mi) {
                int mt = w * 3 + mi;
                bf8_t af = Af[(mt * 16 + ks) * 64 + lane];
                acc[mi] = __builtin_amdgcn_mfma_f32_16x16x32_bf16(af, bf, acc[mi], 0, 0, 0);
            }
        }
        // BN + ReLU, scatter to actL[row][col] (only cols 0-7 are real)
        if (col < 8) {
            #pragma unroll
            for (int mi = 0; mi < 3; ++mi) {
                int rbase = (w * 3 + mi) * 16 + ((lane >> 4) << 2);
                #pragma unroll
                for (int r = 0; r < 4; ++r) {
                    int row = rbase + r;
                    float v = acc[mi][r] * bn1s[row] + bn1h[row];
                    actL[row][col] = fmaxf(v, 0.f);
                }
            }
        }
    }
    __syncthreads();

    // ---- P3a: scores[l][m] = sum_d q[d][l]*k[d][m]  (threads 0..63; 2 lanes per dot)
    if (tid < 64) {
        int s = tid >> 5, l = (tid >> 3) & 3, m = (tid >> 1) & 3, dg = tid & 1;
        float part = 0.f;
        #pragma unroll 8
        for (int k = 0; k < 32; ++k) {
            int d = dg * 32 + k;
            part += actL[d][s * 4 + l] * actL[64 + d][s * 4 + m];
        }
        part += __shfl_xor(part, 1);
        if (dg == 0) smx[s][l * 4 + m] = part;
    }
    __syncthreads();

    // ---- softmax rows (threads 0..7)
    if (tid < 8) {
        int s = tid >> 2, l = tid & 3;
        float s0 = smx[s][l*4+0], s1 = smx[s][l*4+1], s2 = smx[s][l*4+2], s3 = smx[s][l*4+3];
        float mx = fmaxf(fmaxf(s0, s1), fmaxf(s2, s3));
        float e0 = expf(s0-mx), e1 = expf(s1-mx), e2 = expf(s2-mx), e3 = expf(s3-mx);
        float inv = 1.f / (e0 + e1 + e2 + e3);
        smx[s][l*4+0] = e0*inv; smx[s][l*4+1] = e1*inv;
        smx[s][l*4+2] = e2*inv; smx[s][l*4+3] = e3*inv;
    }
    __syncthreads();

    // ---- P3b: att[s][l][d] = sum_m p[l][m]*v[d][m] -> B2 bf16 [col=s*4+l][k=d]
    if (tid < 64) {
        int s = tid >> 5, l = (tid >> 3) & 3, d0 = (tid & 7) * 8;
        float p0 = smx[s][l*4+0], p1 = smx[s][l*4+1], p2 = smx[s][l*4+2], p3 = smx[s][l*4+3];
        #pragma unroll
        for (int j = 0; j < 8; ++j) {
            int d = d0 + j;
            float sum = p0 * actL[128+d][s*4+0] + p1 * actL[128+d][s*4+1]
                      + p2 * actL[128+d][s*4+2] + p3 * actL[128+d][s*4+3];
            B2[s * 4 + l][d] = f2b(sum);
        }
    }
    __syncthreads();

    // ---- GEMM2: C2(512x8) = W4(512x64) @ att(64x8); wave w owns mtiles w*8..w*8+7
    {
        const bf8_t* A2f = (const bf8_t*)w4b;
        const int col = lane & 15, kg = (lane >> 4) << 3;
        f4_t acc2[8] = {};
        #pragma unroll
        for (int ks = 0; ks < 2; ++ks) {
            bf8_t bf = *(const bf8_t*)&B2[col & 7][ks * 32 + kg];
            #pragma unroll
            for (int mi = 0; mi < 8; ++mi) {
                int mt = w * 8 + mi;
                bf8_t af = A2f[(mt * 2 + ks) * 64 + lane];
                acc2[mi] = __builtin_amdgcn_mfma_f32_16x16x32_bf16(af, bf, acc2[mi], 0, 0, 0);
            }
        }
        // BN2 -> C2T[col][c] (cols 0-7 real)
        if (col < 8) {
            #pragma unroll
            for (int mi = 0; mi < 8; ++mi) {
                int cbase = (w * 8 + mi) * 16 + ((lane >> 4) << 2);
                #pragma unroll
                for (int r = 0; r < 4; ++r) {
                    int c = cbase + r;
                    C2T[col][c] = acc2[mi][r] * bn2s[c] + bn2h[c];
                }
            }
        }
    }
    __syncthreads();

    // ---- P5: residual stream, all 256 threads, fully coalesced (32B chunks)
    #pragma unroll
    for (int it = 0; it < 8; ++it) {
        int j = it * 256 + tid;            // j in 0..2047: s = j>>10, c = (j&1023)>>1, half = j&1
        int s = j >> 10, rem = j & 1023, c = rem >> 1, half = rem & 1;
        const float* xp = x + (size_t)(n0 + s) * 8192 + c * 16 + half * 8;
        float* op = out + (size_t)(n0 + s) * 8192 + c * 16 + half * 8;
        float b0 = C2T[s * 4 + half * 2 + 0][c];
        float b1 = C2T[s * 4 + half * 2 + 1][c];
        float4 x0 = *(const float4*)xp;
        float4 x1 = *(const float4*)(xp + 4);
        *(float4*)op       = make_float4(x0.x + b0, x0.y + b0, x0.z + b0, x0.w + b0);
        *(float4*)(op + 4) = make_float4(x1.x + b1, x1.y + b1, x1.z + b1, x1.w + b1);
    }
}

extern "C" void kernel_launch(void* const* d_in, const int* in_sizes, int n_in,
                              void* d_out, int out_size, void* d_ws, size_t ws_size,
                              hipStream_t stream) {
    const float* x     = (const float*)d_in[0];
    const float* W123  = (const float*)d_in[1];
    const float* b123  = (const float*)d_in[2];
    const float* g123  = (const float*)d_in[3];
    const float* be123 = (const float*)d_in[4];
    const float* m123  = (const float*)d_in[5];
    const float* v123  = (const float*)d_in[6];
    const float* W4    = (const float*)d_in[7];
    const float* b4    = (const float*)d_in[8];
    const float* g4    = (const float*)d_in[9];
    const float* be4   = (const float*)d_in[10];
    const float* m4    = (const float*)d_in[11];
    const float* v4    = (const float*)d_in[12];
    float* outp = (float*)d_out;

    char* ws = (char*)d_ws;
    unsigned short* w1b = (unsigned short*)ws;
    unsigned short* w4b = (unsigned short*)(ws + 196608);
    float* bn1s = (float*)(ws + 262144);
    float* bn1h = (float*)(ws + 262912);
    float* bn2s = (float*)(ws + 263680);
    float* bn2h = (float*)(ws + 265728);

    k0_prep<<<65, 256, 0, stream>>>(W123, W4, b123, g123, be123, m123, v123,
                                    b4, g4, be4, m4, v4,
                                    w1b, w4b, bn1s, bn1h, bn2s, bn2h);
    k1_mfma<<<1024, 256, 0, stream>>>(x, w1b, w4b, bn1s, bn1h, bn2s, bn2h, outp);
}